// Round 8
// baseline (62.679 us; speedup 1.0000x reference)
//
#include <hip/hip_runtime.h>
#include <math.h>

#define NWAVE 64
#define DMODEL 128
#define BLOCK 256
#define N_FIXED 768
#define TILE 32          // J-cols per block
#define ROWS 16          // I-rows per block (half of a 32-row tile)
#define T_TILES 24       // 768/32
#define TPAIRS 300       // 24*25/2

// Symmetric tile-pair kernel, attempt 3. R7's VGPR_Count=48 proved the
// jR[32]/jI[32] arrays were demoted to scratch (latency-bound, VALUBusy 19%).
// Fix: 64 NAMED scalar accumulators (macro-generated — no array for the
// compiler to demote), plus row-split blocks (1200 blocks -> 4.7/CU balance).
// One sin/cos serves both directed contributions (r_ij = r_ji, shared
// validI*validJ gate) -> half the trans-pipe work vs R5.
__global__ __launch_bounds__(BLOCK) void spatial_embed_pairs(
    const float* __restrict__ x,            // [B, N, 3]
    const unsigned char* __restrict__ mask, // [B, N] bool (0 = valid)
    float* __restrict__ out,                // [B, N, DMODEL], pre-zeroed
    int B, int N)
{
    __shared__ float xI[ROWS][3], xJ[TILE][3];
    __shared__ float vI[ROWS], vJ[TILE];
    __shared__ __align__(8) float2 pairRV[ROWS * TILE];   // {r, ok/r}
    __shared__ float jaccR[TILE * 64];     // [c][lane] planar, conflict-free
    __shared__ float jaccI[TILE * 64];

    const int tid  = threadIdx.x;
    const int lane = tid & 63;
    const int wid  = tid >> 6;

    // decode (b, it, jt, half): blk = ((b*TPAIRS + tp) << 1) | half
    const int blk  = blockIdx.x;
    const int half = blk & 1;
    int tp = (blk >> 1) % TPAIRS;
    const int b = (blk >> 1) / TPAIRS;
    int it = 0;
    while (tp >= T_TILES - it) { tp -= T_TILES - it; ++it; }
    const int jt = it + tp;
    const bool diag = (it == jt);
    const int arow0 = half * ROWS;          // this half's row offset in the 32-tile
    const int ibase = it * TILE + arow0;
    const int jbase = jt * TILE;

    // ---- phase 0: stage coords + validity ----
    if (tid < ROWS) {
        const int g = b * N + ibase + tid;
        xI[tid][0] = x[g * 3 + 0]; xI[tid][1] = x[g * 3 + 1]; xI[tid][2] = x[g * 3 + 2];
        vI[tid] = (mask[g] == 0) ? 1.0f : 0.0f;
    } else if (tid < ROWS + TILE) {
        const int r = tid - ROWS;
        const int g = b * N + jbase + r;
        xJ[r][0] = x[g * 3 + 0]; xJ[r][1] = x[g * 3 + 1]; xJ[r][2] = x[g * 3 + 2];
        vJ[r] = (mask[g] == 0) ? 1.0f : 0.0f;
    }
    __syncthreads();

    // ---- phase 1: r-subtile + fused validity (2 pairs/thread) ----
    for (int p = tid; p < ROWS * TILE; p += BLOCK) {
        const int a = p >> 5, c = p & (TILE - 1);
        const float dx = xI[a][0] - xJ[c][0];
        const float dy = xI[a][1] - xJ[c][1];
        const float dz = xI[a][2] - xJ[c][2];
        const float d2 = fmaf(dx, dx, fmaf(dy, dy, fmaf(dz, dz, 1e-6f)));
        const float irs = __frsqrt_rn(d2);
        float ok = vI[a] * vJ[c];
        if (diag && (arow0 + a) >= c) ok = 0.0f;   // diag: strictly upper only
        pairRV[p] = make_float2(d2 * irs, ok * irs);
    }
    __syncthreads();

    // ---- phase 2: register-only accumulation, NAMED scalars ----
    const float invlam = 0.5f * exp2f((float)lane * -0.07371200301229721f);

#define JDECL(c) float jR##c = 0.0f, jI##c = 0.0f;
    JDECL(0)  JDECL(1)  JDECL(2)  JDECL(3)  JDECL(4)  JDECL(5)  JDECL(6)  JDECL(7)
    JDECL(8)  JDECL(9)  JDECL(10) JDECL(11) JDECL(12) JDECL(13) JDECL(14) JDECL(15)
    JDECL(16) JDECL(17) JDECL(18) JDECL(19) JDECL(20) JDECL(21) JDECL(22) JDECL(23)
    JDECL(24) JDECL(25) JDECL(26) JDECL(27) JDECL(28) JDECL(29) JDECL(30) JDECL(31)
#undef JDECL

#define DO_COL(c) { \
    const float2 p = rowp[c]; \
    const float rev = p.x * invlam; \
    const float sn = __builtin_amdgcn_sinf(rev); \
    const float cs = __builtin_amdgcn_cosf(rev); \
    aR = fmaf(cs, p.y, aR);          aI = fmaf(sn, p.y, aI); \
    jR##c = fmaf(cs, p.y, jR##c);    jI##c = fmaf(sn, p.y, jI##c); }

#define DO_ROW(RL) { \
    const int row = wid * 4 + (RL); \
    const float2* rowp = &pairRV[row * TILE]; \
    float aR = 0.0f, aI = 0.0f; \
    DO_COL(0)  DO_COL(1)  DO_COL(2)  DO_COL(3)  DO_COL(4)  DO_COL(5)  DO_COL(6)  DO_COL(7) \
    DO_COL(8)  DO_COL(9)  DO_COL(10) DO_COL(11) DO_COL(12) DO_COL(13) DO_COL(14) DO_COL(15) \
    DO_COL(16) DO_COL(17) DO_COL(18) DO_COL(19) DO_COL(20) DO_COL(21) DO_COL(22) DO_COL(23) \
    DO_COL(24) DO_COL(25) DO_COL(26) DO_COL(27) DO_COL(28) DO_COL(29) DO_COL(30) DO_COL(31) \
    const int grow = b * N + ibase + row; \
    atomicAdd(&out[grow * DMODEL + 2 * lane],     aR); \
    atomicAdd(&out[grow * DMODEL + 2 * lane + 1], aI); }

    DO_ROW(0) DO_ROW(1) DO_ROW(2) DO_ROW(3)
#undef DO_ROW
#undef DO_COL

    // ---- phase 3: J-side cross-wave reduce (sequential, non-atomic LDS) ----
#define JST(c)  { jaccR[(c) * 64 + lane]  = jR##c;  jaccI[(c) * 64 + lane]  = jI##c; }
#define JADD(c) { jaccR[(c) * 64 + lane] += jR##c;  jaccI[(c) * 64 + lane] += jI##c; }
    for (int p = 0; p < 4; ++p) {
        if (wid == p) {
            if (p == 0) {
                JST(0)  JST(1)  JST(2)  JST(3)  JST(4)  JST(5)  JST(6)  JST(7)
                JST(8)  JST(9)  JST(10) JST(11) JST(12) JST(13) JST(14) JST(15)
                JST(16) JST(17) JST(18) JST(19) JST(20) JST(21) JST(22) JST(23)
                JST(24) JST(25) JST(26) JST(27) JST(28) JST(29) JST(30) JST(31)
            } else {
                JADD(0)  JADD(1)  JADD(2)  JADD(3)  JADD(4)  JADD(5)  JADD(6)  JADD(7)
                JADD(8)  JADD(9)  JADD(10) JADD(11) JADD(12) JADD(13) JADD(14) JADD(15)
                JADD(16) JADD(17) JADD(18) JADD(19) JADD(20) JADD(21) JADD(22) JADD(23)
                JADD(24) JADD(25) JADD(26) JADD(27) JADD(28) JADD(29) JADD(30) JADD(31)
            }
        }
        __syncthreads();
    }
#undef JST
#undef JADD

    // ---- phase 4: J-side flush ----
    for (int k = tid; k < TILE * 64; k += BLOCK) {
        const int c = k >> 6, w = k & 63;
        const int grow = b * N + jbase + c;
        atomicAdd(&out[grow * DMODEL + 2 * w],     jaccR[k]);
        atomicAdd(&out[grow * DMODEL + 2 * w + 1], jaccI[k]);
    }
}

extern "C" void kernel_launch(void* const* d_in, const int* in_sizes, int n_in,
                              void* d_out, int out_size, void* d_ws, size_t ws_size,
                              hipStream_t stream) {
    const float* x = (const float*)d_in[0];
    const unsigned char* mask = (const unsigned char*)d_in[1];
    float* out = (float*)d_out;

    const int N = N_FIXED;
    const int BN = in_sizes[1];              // B*N
    const int B = BN / N;

    hipMemsetAsync(d_out, 0, (size_t)out_size * sizeof(float), stream);
    spatial_embed_pairs<<<dim3(B * TPAIRS * 2), dim3(BLOCK), 0, stream>>>(x, mask, out, B, N);
}

// Round 9
// 31.547 us; speedup vs baseline: 1.9869x; 1.9869x over previous
//
#include <hip/hip_runtime.h>
#include <math.h>

#define NWAVE 64
#define DMODEL 128
#define BLOCK 256
#define N_FIXED 768
#define TILE 32
#define T_TILES 24       // 768/32
#define TPAIRS 300       // 24*25/2
#define NSLOT 25
// ws layout: ws[(( b*T_TILES + t )*NSLOT + slot)*TILE*DMODEL + row*DMODEL + col]
// target tile t receives: nondiag-J at slots {0..t-1}, I at slots {t..23}, diag-J at {24}
#define WS_FLOATS_PER_TILE (NSLOT * TILE * DMODEL)          // 25*4096 = 102400
#define WS_FLOATS_PER_B   ((size_t)T_TILES * WS_FLOATS_PER_TILE)

// Symmetric tile-pair kernel, attempt 4. R7/R8's VGPR_Count=48 was the
// allocator's default occupancy target spilling the accumulators — fix is
// __launch_bounds__(256, 2) (VGPR cap 256). Global atomics (8B/atomic of
// WRITE traffic, suspected 10-25us tax) replaced by plain stores of
// per-tile-pair partials into d_ws + a BW-bound reduce kernel.
template <bool USE_WS>
__global__ __launch_bounds__(BLOCK, 2) void spatial_embed_pairs(
    const float* __restrict__ x,            // [B, N, 3]
    const unsigned char* __restrict__ mask, // [B, N] bool (0 = valid)
    float* __restrict__ out,                // used only when !USE_WS (pre-zeroed)
    float* __restrict__ ws,                 // used only when USE_WS
    int B, int N)
{
    __shared__ float xI[TILE][3], xJ[TILE][3];
    __shared__ float vI[TILE], vJ[TILE];
    __shared__ __align__(16) float2 pairRV[TILE * TILE];  // {r, ok/r}
    __shared__ float jaccR[TILE * 64];     // [c][lane] planar, conflict-free
    __shared__ float jaccI[TILE * 64];

    const int tid  = threadIdx.x;
    const int lane = tid & 63;
    const int wid  = tid >> 6;

    // decode (b, it, jt), it <= jt
    int tp = blockIdx.x % TPAIRS;
    const int b = blockIdx.x / TPAIRS;
    int it = 0;
    while (tp >= T_TILES - it) { tp -= T_TILES - it; ++it; }
    const int jt = it + tp;
    const bool diag = (it == jt);
    const int ibase = it * TILE, jbase = jt * TILE;

    // ---- phase 0: stage coords + validity ----
    if (tid < TILE) {
        const int g = b * N + ibase + tid;
        xI[tid][0] = x[g * 3 + 0]; xI[tid][1] = x[g * 3 + 1]; xI[tid][2] = x[g * 3 + 2];
        vI[tid] = (mask[g] == 0) ? 1.0f : 0.0f;
    } else if (tid < 2 * TILE) {
        const int r = tid - TILE;
        const int g = b * N + jbase + r;
        xJ[r][0] = x[g * 3 + 0]; xJ[r][1] = x[g * 3 + 1]; xJ[r][2] = x[g * 3 + 2];
        vJ[r] = (mask[g] == 0) ? 1.0f : 0.0f;
    }
    __syncthreads();

    // ---- phase 1: r-tile + fused validity (4 pairs/thread) ----
    for (int p = tid; p < TILE * TILE; p += BLOCK) {
        const int a = p >> 5, c = p & (TILE - 1);
        const float dx = xI[a][0] - xJ[c][0];
        const float dy = xI[a][1] - xJ[c][1];
        const float dz = xI[a][2] - xJ[c][2];
        const float d2 = fmaf(dx, dx, fmaf(dy, dy, fmaf(dz, dz, 1e-6f)));
        const float irs = rsqrtf(d2);           // v_rsq_f32
        float ok = vI[a] * vJ[c];
        if (diag && a >= c) ok = 0.0f;          // diag: strictly upper only
        pairRV[p] = make_float2(d2 * irs, ok * irs);  // {r, ok/r}
    }
    __syncthreads();

    // ---- phase 2: register-only accumulation (wave owns 8 rows x 32 cols) ----
    const float invlam = 0.5f * exp2f((float)lane * -0.07371200301229721f);

#define JDECL(c) float jR##c = 0.0f, jI##c = 0.0f;
    JDECL(0)  JDECL(1)  JDECL(2)  JDECL(3)  JDECL(4)  JDECL(5)  JDECL(6)  JDECL(7)
    JDECL(8)  JDECL(9)  JDECL(10) JDECL(11) JDECL(12) JDECL(13) JDECL(14) JDECL(15)
    JDECL(16) JDECL(17) JDECL(18) JDECL(19) JDECL(20) JDECL(21) JDECL(22) JDECL(23)
    JDECL(24) JDECL(25) JDECL(26) JDECL(27) JDECL(28) JDECL(29) JDECL(30) JDECL(31)
#undef JDECL

#define DO_Q(Q,CA,CB) { \
    const float4 qq = rowp4[Q]; \
    { const float rev = qq.x * invlam; \
      const float sn = __builtin_amdgcn_sinf(rev); \
      const float cs = __builtin_amdgcn_cosf(rev); \
      aR = fmaf(cs, qq.y, aR);            aI = fmaf(sn, qq.y, aI); \
      jR##CA = fmaf(cs, qq.y, jR##CA);    jI##CA = fmaf(sn, qq.y, jI##CA); } \
    { const float rev = qq.z * invlam; \
      const float sn = __builtin_amdgcn_sinf(rev); \
      const float cs = __builtin_amdgcn_cosf(rev); \
      aR = fmaf(cs, qq.w, aR);            aI = fmaf(sn, qq.w, aI); \
      jR##CB = fmaf(cs, qq.w, jR##CB);    jI##CB = fmaf(sn, qq.w, jI##CB); } }

#define DO_ROW(RL) { \
    const int row = wid * 8 + (RL); \
    const float4* rowp4 = (const float4*)&pairRV[row * TILE]; \
    float aR = 0.0f, aI = 0.0f; \
    DO_Q(0,0,1)   DO_Q(1,2,3)   DO_Q(2,4,5)   DO_Q(3,6,7) \
    DO_Q(4,8,9)   DO_Q(5,10,11) DO_Q(6,12,13) DO_Q(7,14,15) \
    DO_Q(8,16,17) DO_Q(9,18,19) DO_Q(10,20,21) DO_Q(11,22,23) \
    DO_Q(12,24,25) DO_Q(13,26,27) DO_Q(14,28,29) DO_Q(15,30,31) \
    if constexpr (USE_WS) { \
        float* dst = ws + (((size_t)(b * T_TILES + it) * NSLOT + jt) * TILE + row) * DMODEL; \
        ((float2*)dst)[lane] = make_float2(aR, aI); \
    } else { \
        const int grow = b * N + ibase + row; \
        atomicAdd(&out[grow * DMODEL + 2 * lane],     aR); \
        atomicAdd(&out[grow * DMODEL + 2 * lane + 1], aI); \
    } }

    DO_ROW(0) DO_ROW(1) DO_ROW(2) DO_ROW(3)
    DO_ROW(4) DO_ROW(5) DO_ROW(6) DO_ROW(7)
#undef DO_ROW
#undef DO_Q

    // ---- phase 3: J-side cross-wave reduce (sequential, non-atomic LDS) ----
#define JST(c)  { jaccR[(c) * 64 + lane]  = jR##c;  jaccI[(c) * 64 + lane]  = jI##c; }
#define JADD(c) { jaccR[(c) * 64 + lane] += jR##c;  jaccI[(c) * 64 + lane] += jI##c; }
    for (int p = 0; p < 4; ++p) {
        if (wid == p) {
            if (p == 0) {
                JST(0)  JST(1)  JST(2)  JST(3)  JST(4)  JST(5)  JST(6)  JST(7)
                JST(8)  JST(9)  JST(10) JST(11) JST(12) JST(13) JST(14) JST(15)
                JST(16) JST(17) JST(18) JST(19) JST(20) JST(21) JST(22) JST(23)
                JST(24) JST(25) JST(26) JST(27) JST(28) JST(29) JST(30) JST(31)
            } else {
                JADD(0)  JADD(1)  JADD(2)  JADD(3)  JADD(4)  JADD(5)  JADD(6)  JADD(7)
                JADD(8)  JADD(9)  JADD(10) JADD(11) JADD(12) JADD(13) JADD(14) JADD(15)
                JADD(16) JADD(17) JADD(18) JADD(19) JADD(20) JADD(21) JADD(22) JADD(23)
                JADD(24) JADD(25) JADD(26) JADD(27) JADD(28) JADD(29) JADD(30) JADD(31)
            }
        }
        __syncthreads();
    }
#undef JST
#undef JADD

    // ---- phase 4: J-side flush ----
    const int slotJ = diag ? (NSLOT - 1) : it;
    for (int k = tid; k < TILE * 64; k += BLOCK) {
        const int c = k >> 6, w = k & 63;
        if constexpr (USE_WS) {
            float* dst = ws + (((size_t)(b * T_TILES + jt) * NSLOT + slotJ) * TILE + c) * DMODEL;
            ((float2*)dst)[w] = make_float2(jaccR[k], jaccI[k]);
        } else {
            const int grow = b * N + jbase + c;
            atomicAdd(&out[grow * DMODEL + 2 * w],     jaccR[k]);
            atomicAdd(&out[grow * DMODEL + 2 * w + 1], jaccI[k]);
        }
    }
}

// Sum the 25 slots per output tile. grid = B*T_TILES*4 blocks; each block
// handles 1024 consecutive floats (256 thr x float4). Fixed slot order ->
// deterministic. Masked query rows: all their partials are 0 -> out = 0.
__global__ __launch_bounds__(BLOCK) void reduce_ws(
    const float* __restrict__ ws, float* __restrict__ out)
{
    const int blk   = blockIdx.x;
    const int chunk = blk & 3;             // 4 chunks of 1024 floats per tile
    const int bt    = blk >> 2;            // b*T_TILES + t
    const int e4    = chunk * 256 + threadIdx.x;   // float4 index in [0,1024)
    const float4* base = (const float4*)(ws + (size_t)bt * WS_FLOATS_PER_TILE) + e4;
    float4 s = make_float4(0.f, 0.f, 0.f, 0.f);
    #pragma unroll
    for (int sl = 0; sl < NSLOT; ++sl) {
        const float4 v = base[sl * (TILE * DMODEL / 4)];
        s.x += v.x; s.y += v.y; s.z += v.z; s.w += v.w;
    }
    ((float4*)(out + (size_t)bt * TILE * DMODEL))[e4] = s;
}

extern "C" void kernel_launch(void* const* d_in, const int* in_sizes, int n_in,
                              void* d_out, int out_size, void* d_ws, size_t ws_size,
                              hipStream_t stream) {
    const float* x = (const float*)d_in[0];
    const unsigned char* mask = (const unsigned char*)d_in[1];
    float* out = (float*)d_out;
    float* ws  = (float*)d_ws;

    const int N = N_FIXED;
    const int BN = in_sizes[1];              // B*N
    const int B = BN / N;

    const size_t ws_need = (size_t)B * WS_FLOATS_PER_B * sizeof(float);
    if (ws_size >= ws_need) {
        spatial_embed_pairs<true><<<dim3(B * TPAIRS), dim3(BLOCK), 0, stream>>>(
            x, mask, out, ws, B, N);
        reduce_ws<<<dim3(B * T_TILES * 4), dim3(BLOCK), 0, stream>>>(ws, out);
    } else {
        hipMemsetAsync(d_out, 0, (size_t)out_size * sizeof(float), stream);
        spatial_embed_pairs<false><<<dim3(B * TPAIRS), dim3(BLOCK), 0, stream>>>(
            x, mask, out, ws, B, N);
    }
}